// Round 8
// baseline (85.754 us; speedup 1.0000x reference)
//
#include <hip/hip_runtime.h>

// X [B=8, L=4096, D=1024] fp32.  O = (L*X - colsum_over_L) / (L-1).
// Two-kernel split:
//   K1: per-(b,d) colsum -> c[b,d] = -colsum/(L-1)   (32 KB into d_ws)
//       pure HBM read of X at full read rate; warms L3 with X.
//   K2: O = (L/(L-1))*X + c[b,d]  -- pure streaming FMA, no barriers;
//       loads/stores interleave at instruction granularity (mixed HBM traffic),
//       X re-read mostly hits Infinity Cache.
constexpr int Bn = 8;
constexpr int Ln = 4096;
constexpr int Dn = 1024;

typedef float f32x4 __attribute__((ext_vector_type(4)));

// ---------------- K1: colsum ----------------
constexpr int TD  = 16;          // cols per block -> 64 tiles/batch, 512 blocks
constexpr int NT  = 1024;        // 16 waves
constexpr int QPB = TD / 4;      // 4 quads per tile row
constexpr int RPI = NT / QPB;    // 256 rows per iteration
constexpr int NIT = Ln / RPI;    // 16 iterations
constexpr int NW  = NT / 64;     // 16 waves

__global__ __launch_bounds__(NT) void colsum_kernel(
    const float* __restrict__ X, float* __restrict__ C) {
    const int tid  = threadIdx.x;
    const int lane = tid & 63;
    const int w    = tid >> 6;
    const int b    = blockIdx.x >> 6;
    const int tile = blockIdx.x & 63;
    const int q    = tid & (QPB - 1);
    const int g    = tid >> 2;

    const size_t base = (size_t)b * Ln * Dn + (size_t)tile * TD
                      + (size_t)q * 4 + (size_t)g * Dn;
    constexpr size_t STR = (size_t)RPI * Dn;

    f32x4 a0 = (f32x4)0.f, a1 = (f32x4)0.f, a2 = (f32x4)0.f, a3 = (f32x4)0.f;
#pragma unroll
    for (int it = 0; it < NIT; it += 4) {
        a0 += *reinterpret_cast<const f32x4*>(X + base + (size_t)(it + 0) * STR);
        a1 += *reinterpret_cast<const f32x4*>(X + base + (size_t)(it + 1) * STR);
        a2 += *reinterpret_cast<const f32x4*>(X + base + (size_t)(it + 2) * STR);
        a3 += *reinterpret_cast<const f32x4*>(X + base + (size_t)(it + 3) * STR);
    }
    f32x4 acc = (a0 + a1) + (a2 + a3);

    // wave butterfly over the 16 row-groups (lane = q + 4*group)
#pragma unroll
    for (int m = QPB; m <= 32; m <<= 1) {
        f32x4 o;
        o.x = __shfl_xor(acc.x, m);
        o.y = __shfl_xor(acc.y, m);
        o.z = __shfl_xor(acc.z, m);
        o.w = __shfl_xor(acc.w, m);
        acc += o;
    }

    __shared__ f32x4 red[NW * QPB];   // 1 KiB
    if (lane < QPB) red[w * QPB + q] = acc;
    __syncthreads();

    if (tid < QPB) {                  // q == tid for tid<4
        f32x4 tot = (f32x4)0.f;
#pragma unroll
        for (int ww = 0; ww < NW; ++ww) tot += red[ww * QPB + tid];
        const float ninv = -1.0f / (float)(Ln - 1);
        reinterpret_cast<f32x4*>(C)[b * (Dn / 4) + tile * QPB + tid] = tot * ninv;
    }
}

// ---------------- K2: apply ----------------
constexpr int AT   = 256;                       // threads per block
constexpr int ABLK = 2048;                      // blocks -> 32 waves/CU
constexpr size_t NV4 = (size_t)Bn * Ln * Dn / 4;  // 8388608 f32x4

__global__ __launch_bounds__(AT) void apply_kernel(
    const float* __restrict__ X, const float* __restrict__ C,
    float* __restrict__ O) {
    const float a = (float)Ln / (float)(Ln - 1);
    const f32x4* __restrict__ X4 = reinterpret_cast<const f32x4*>(X);
    const f32x4* __restrict__ C4 = reinterpret_cast<const f32x4*>(C);
    f32x4* __restrict__ O4 = reinterpret_cast<f32x4*>(O);

    const size_t stride = (size_t)ABLK * AT;
    for (size_t i = (size_t)blockIdx.x * AT + threadIdx.x; i < NV4; i += stride) {
        const f32x4 x = X4[i];
        // element index e = 4i: d4 = i & 255, b = i >> 20 (L*D/4 = 1M per batch)
        const f32x4 c = C4[((i >> 20) << 8) + (i & 255)];   // L2-resident 32 KB
        O4[i] = a * x + c;
    }
}

extern "C" void kernel_launch(void* const* d_in, const int* in_sizes, int n_in,
                              void* d_out, int out_size, void* d_ws, size_t ws_size,
                              hipStream_t stream) {
    (void)in_sizes; (void)n_in; (void)ws_size; (void)out_size;
    const float* X = (const float*)d_in[0];
    float* O = (float*)d_out;
    float* C = (float*)d_ws;          // 32 KB of scratch for per-column offsets

    colsum_kernel<<<Bn * (Dn / TD), NT, 0, stream>>>(X, C);
    apply_kernel<<<ABLK, AT, 0, stream>>>(X, C, O);
}